// Round 23
// baseline (121.867 us; speedup 1.0000x reference)
//
#include <hip/hip_runtime.h>
#include <stdint.h>

#define C 128
#define ALPHA_F 0.1f
#define ONE_MINUS_ALPHA 0.9f
// beta = log(THETA/LAYER + 1) = log(1.25)
#define BETA_F 0.22314355131420976f
#define ONE_MINUS_BETA 0.7768564486857902f
#define KSLOT 16

typedef __attribute__((ext_vector_type(8))) short bf16x8;
typedef __attribute__((ext_vector_type(4))) float f32x4;

__device__ inline float bf2f(unsigned short u) {
    union { unsigned int i; float f; } c;
    c.i = ((unsigned int)u) << 16;
    return c.f;
}
__device__ inline unsigned short f2bf(float f) {
    union { float f; unsigned int i; } c;
    c.f = f;
    unsigned int r = (c.i + 0x7FFFu + ((c.i >> 16) & 1u)) >> 16;  // RNE
    return (unsigned short)r;
}

// ---- init: zero cnt + ovf counter + V = (1-beta)*I + beta*W^T (bf16) ----
// (kernel zero, NOT hipMemsetAsync: runtime fill kernel measured 40us/400KB.
//  NOT cooperative mega-kernel: grid.sync measured ~100us-class on 8 XCDs.)
__global__ void k_init(const float* __restrict__ W, unsigned short* __restrict__ Vb,
                       int* __restrict__ cnt, int* __restrict__ ovf_cnt, int n) {
    int i = blockIdx.x * 256 + threadIdx.x;
    if (i == 0) *ovf_cnt = 0;
    if (i < n) cnt[i] = 0;
    if (i < C * C) {
        int j = i >> 7;   // W row = output index
        int c = i & 127;  // k index
        float v = BETA_F * W[i] + ((j == c) ? ONE_MINUS_BETA : 0.f);
        Vb[i] = f2bf(v);
    }
}

// hist + DIRECT placement into fixed-stride CSR (row_ptr == d*KSLOT; the
// atomic's return value is the slot index). Slot store is NONTEMPORAL:
// round-22 counters showed 39.5MB WRITE for 2.6MB payload — every scattered
// 4B store forced a 64B line acquire+writeback (cross-XCD ping-pong).
__global__ void k_hist_place(const int* __restrict__ src, const int* __restrict__ dst,
                             int* __restrict__ cnt, int* __restrict__ sorted_src,
                             int* __restrict__ ovf_src, int* __restrict__ ovf_dst,
                             int* __restrict__ ovf_cnt, int e) {
    int i = blockIdx.x * blockDim.x + threadIdx.x;
    if (i < e) {
        int d = dst[i];
        int r = atomicAdd(&cnt[d], 1);
        if (r < KSLOT) {
            __builtin_nontemporal_store(src[i], &sorted_src[(size_t)d * KSLOT + r]);
        } else {
            int p = atomicAdd(ovf_cnt, 1);
            ovf_src[p] = src[i];
            ovf_dst[p] = d;
        }
    }
}

// y[i][:] = bf16(x[i][:] * rsqrt(deg_i+1)); dinv recomputed from cnt (no array)
__global__ void k_ybf(const float* __restrict__ x, const int* __restrict__ cnt,
                      unsigned short* __restrict__ y, int n) {
    int t = blockIdx.x * 256 + threadIdx.x;
    int total = n * 32;
    if (t < total) {
        int i = t >> 5;
        float dv = rsqrtf((float)(cnt[i] + 1));
        float4 v = ((const float4*)x)[t];
        ushort4 o;
        o.x = f2bf(v.x * dv);
        o.y = f2bf(v.y * dv);
        o.z = f2bf(v.z * dv);
        o.w = f2bf(v.w * dv);
        ((ushort4*)y)[t] = o;
    }
}

// per-node accumulate: 8 weight-clamped up-front loads + one 4-wide batch to
// KSLOT=16. eidx = this half-wave's preloaded edge list (coalesced 64B read).
__device__ __forceinline__ float4 acc_node(const ushort4* __restrict__ y4,
                                           int node, int len,
                                           int eidx, int l32, int base) {
    int m = (len < KSLOT) ? len : KSLOT;
    bool b1 = 1 < m, b2 = 2 < m, b3 = 3 < m;
    bool b4 = 4 < m, b5 = 5 < m, b6 = 6 < m, b7 = 7 < m;
    int s0 = __shfl(eidx, base + 0, 64);
    int s1 = __shfl(eidx, base + (b1 ? 1 : 0), 64);
    int s2 = __shfl(eidx, base + (b2 ? 2 : 0), 64);
    int s3 = __shfl(eidx, base + (b3 ? 3 : 0), 64);
    int s4 = __shfl(eidx, base + (b4 ? 4 : 0), 64);
    int s5 = __shfl(eidx, base + (b5 ? 5 : 0), 64);
    int s6 = __shfl(eidx, base + (b6 ? 6 : 0), 64);
    int s7 = __shfl(eidx, base + (b7 ? 7 : 0), 64);
    ushort4 v0 = y4[(size_t)s0 * 32 + l32];
    ushort4 v1 = y4[(size_t)s1 * 32 + l32];
    ushort4 v2 = y4[(size_t)s2 * 32 + l32];
    ushort4 v3 = y4[(size_t)s3 * 32 + l32];
    ushort4 v4 = y4[(size_t)s4 * 32 + l32];
    ushort4 v5 = y4[(size_t)s5 * 32 + l32];
    ushort4 v6 = y4[(size_t)s6 * 32 + l32];
    ushort4 v7 = y4[(size_t)s7 * 32 + l32];
    ushort4 vs = y4[(size_t)node * 32 + l32];   // self-loop row

    float w0 = (0 < m) ? 1.f : 0.f, w1 = b1 ? 1.f : 0.f, w2 = b2 ? 1.f : 0.f, w3 = b3 ? 1.f : 0.f;
    float w4 = b4 ? 1.f : 0.f, w5 = b5 ? 1.f : 0.f, w6 = b6 ? 1.f : 0.f, w7 = b7 ? 1.f : 0.f;

    float4 acc;
    acc.x = bf2f(vs.x) + w0 * bf2f(v0.x) + w1 * bf2f(v1.x) + w2 * bf2f(v2.x) + w3 * bf2f(v3.x)
                       + w4 * bf2f(v4.x) + w5 * bf2f(v5.x) + w6 * bf2f(v6.x) + w7 * bf2f(v7.x);
    acc.y = bf2f(vs.y) + w0 * bf2f(v0.y) + w1 * bf2f(v1.y) + w2 * bf2f(v2.y) + w3 * bf2f(v3.y)
                       + w4 * bf2f(v4.y) + w5 * bf2f(v5.y) + w6 * bf2f(v6.y) + w7 * bf2f(v7.y);
    acc.z = bf2f(vs.z) + w0 * bf2f(v0.z) + w1 * bf2f(v1.z) + w2 * bf2f(v2.z) + w3 * bf2f(v3.z)
                       + w4 * bf2f(v4.z) + w5 * bf2f(v5.z) + w6 * bf2f(v6.z) + w7 * bf2f(v7.z);
    acc.w = bf2f(vs.w) + w0 * bf2f(v0.w) + w1 * bf2f(v1.w) + w2 * bf2f(v2.w) + w3 * bf2f(v3.w)
                       + w4 * bf2f(v4.w) + w5 * bf2f(v5.w) + w6 * bf2f(v6.w) + w7 * bf2f(v7.w);

    for (int j = 8; j < m; j += 4) {     // 9..16 incident edges (one batch)
        bool c1 = (j + 1) < m, c2 = (j + 2) < m, c3 = (j + 3) < m;
        int t0 = __shfl(eidx, base + j, 64);
        int t1 = __shfl(eidx, base + (c1 ? j + 1 : j), 64);
        int t2 = __shfl(eidx, base + (c2 ? j + 2 : j), 64);
        int t3 = __shfl(eidx, base + (c3 ? j + 3 : j), 64);
        ushort4 u0 = y4[(size_t)t0 * 32 + l32];
        ushort4 u1 = y4[(size_t)t1 * 32 + l32];
        ushort4 u2 = y4[(size_t)t2 * 32 + l32];
        ushort4 u3 = y4[(size_t)t3 * 32 + l32];
        float q1 = c1 ? 1.f : 0.f, q2 = c2 ? 1.f : 0.f, q3 = c3 ? 1.f : 0.f;
        acc.x += bf2f(u0.x) + q1 * bf2f(u1.x) + q2 * bf2f(u2.x) + q3 * bf2f(u3.x);
        acc.y += bf2f(u0.y) + q1 * bf2f(u1.y) + q2 * bf2f(u2.y) + q3 * bf2f(u3.y);
        acc.z += bf2f(u0.z) + q1 * bf2f(u1.z) + q2 * bf2f(u2.z) + q3 * bf2f(u3.z);
        acc.w += bf2f(u0.w) + q1 * bf2f(u1.w) + q2 * bf2f(u2.w) + q3 * bf2f(u3.w);
    }
    return acc;
}

// overflow edges for this node (deg > KSLOT): scan the short overflow list,
// filter by dst == node. Correct for any degree distribution.
__device__ __forceinline__ float4 add_ovf(float4 acc, const ushort4* __restrict__ y4,
                                          const int* __restrict__ ovf_src,
                                          const int* __restrict__ ovf_dst,
                                          int oc, int node, int l32) {
    for (int j = 0; j < oc; ++j) {
        if (ovf_dst[j] == node) {
            ushort4 u = y4[(size_t)ovf_src[j] * 32 + l32];
            acc.x += bf2f(u.x);
            acc.y += bf2f(u.y);
            acc.z += bf2f(u.z);
            acc.w += bf2f(u.w);
        }
    }
    return acc;
}

// ---------------- gather + alpha-blend -> s (bf16 ws or fp32 d_out) --------
// 2 nodes per HALF-WAVE, front-loads paired (kernel-level 42.8 -> 40.0us).
__global__ __launch_bounds__(256)
void k_gather(const unsigned short* __restrict__ y, const float* __restrict__ x0,
              const int* __restrict__ sorted_src, const int* __restrict__ cnt,
              const int* __restrict__ ovf_src, const int* __restrict__ ovf_dst,
              const int* __restrict__ ovf_cnt,
              float* __restrict__ soutf, unsigned short* __restrict__ soutb,
              int mode, int n) {
    int tid  = threadIdx.x;
    int l32  = tid & 31;
    int base = tid & 32;
    int hw   = tid >> 5;                  // 0..7 half-wave in block
    int node0 = blockIdx.x * 16 + hw * 2;
    if (node0 >= n) return;
    int node1 = node0 + 1;
    bool ok1 = node1 < n;
    int vn1 = ok1 ? node1 : node0;

    const ushort4* y4 = (const ushort4*)y;
    const f32x4* x04 = (const f32x4*)x0;

    // paired front-loads (all independent); lanes 16..31 pad to self index
    int len0 = cnt[node0];
    int len1 = cnt[vn1];
    int m0 = (len0 < KSLOT) ? len0 : KSLOT;
    int m1 = (len1 < KSLOT) ? len1 : KSLOT;
    int e0 = (l32 < m0) ? sorted_src[(size_t)node0 * KSLOT + l32] : node0;
    int e1 = (l32 < m1) ? sorted_src[(size_t)vn1 * KSLOT + l32] : vn1;
    f32x4 xv0 = __builtin_nontemporal_load(x04 + (size_t)node0 * 32 + l32);
    f32x4 xv1 = __builtin_nontemporal_load(x04 + (size_t)vn1 * 32 + l32);

    float4 a0 = acc_node(y4, node0, len0, e0, l32, base);
    float4 a1 = acc_node(y4, vn1,   len1, e1, l32, base);

    if (len0 > KSLOT || len1 > KSLOT) {   // rare; correct for any input
        int oc = *ovf_cnt;
        if (len0 > KSLOT) a0 = add_ovf(a0, y4, ovf_src, ovf_dst, oc, node0, l32);
        if (len1 > KSLOT) a1 = add_ovf(a1, y4, ovf_src, ovf_dst, oc, vn1, l32);
    }

    float dv0 = rsqrtf((float)(len0 + 1));
    float dv1 = rsqrtf((float)(len1 + 1));

    float4 s0, s1;
    s0.x = ONE_MINUS_ALPHA * (dv0 * a0.x) + ALPHA_F * xv0.x;
    s0.y = ONE_MINUS_ALPHA * (dv0 * a0.y) + ALPHA_F * xv0.y;
    s0.z = ONE_MINUS_ALPHA * (dv0 * a0.z) + ALPHA_F * xv0.z;
    s0.w = ONE_MINUS_ALPHA * (dv0 * a0.w) + ALPHA_F * xv0.w;
    s1.x = ONE_MINUS_ALPHA * (dv1 * a1.x) + ALPHA_F * xv1.x;
    s1.y = ONE_MINUS_ALPHA * (dv1 * a1.y) + ALPHA_F * xv1.y;
    s1.z = ONE_MINUS_ALPHA * (dv1 * a1.z) + ALPHA_F * xv1.z;
    s1.w = ONE_MINUS_ALPHA * (dv1 * a1.w) + ALPHA_F * xv1.w;

    if (mode) {
        unsigned long long p0 =
            (unsigned long long)f2bf(s0.x)
          | ((unsigned long long)f2bf(s0.y) << 16)
          | ((unsigned long long)f2bf(s0.z) << 32)
          | ((unsigned long long)f2bf(s0.w) << 48);
        __builtin_nontemporal_store(
            p0, (unsigned long long*)(soutb + (size_t)node0 * C + l32 * 4));
        if (ok1) {
            unsigned long long p1 =
                (unsigned long long)f2bf(s1.x)
              | ((unsigned long long)f2bf(s1.y) << 16)
              | ((unsigned long long)f2bf(s1.z) << 32)
              | ((unsigned long long)f2bf(s1.w) << 48);
            __builtin_nontemporal_store(
                p1, (unsigned long long*)(soutb + (size_t)node1 * C + l32 * 4));
        }
    } else {
        ((float4*)soutf)[(size_t)node0 * 32 + l32] = s0;
        if (ok1) ((float4*)soutf)[(size_t)node1 * 32 + l32] = s1;
    }
}

// ---------------- MFMA GEMM: out = s @ V + beta*b ----------------
// B (Vb) LDS-staged — round 11 proved B MUST be LDS (32 scattered loads/wave
// from global = 50us kernel). A-fragments straight from global (round 18:
// 126.3 -> 122.9us): only 4 loads/wave/k-step against L3-resident sb16.
__global__ __launch_bounds__(256)
void k_out(const float* __restrict__ sinf, const unsigned short* __restrict__ sinb,
           const unsigned short* __restrict__ Vb, const float* __restrict__ bias,
           float* __restrict__ out, int mode, int n) {
    __shared__ unsigned short wlds[128 * 128];  // 32 KB

    int tid  = threadIdx.x;
    int row0 = blockIdx.x * 64;

    const uint4* Vb16 = (const uint4*)Vb;
    for (int i = tid; i < 2048; i += 256) {
        int j = i >> 4;
        int g = i & 15;
        uint4 v = Vb16[i];
        *(uint4*)&wlds[j * 128 + (g ^ (j & 7)) * 8] = v;
    }
    __syncthreads();

    int w    = tid >> 6;
    int lane = tid & 63;
    int l16  = lane & 15;
    int h    = lane >> 4;
    int arow = row0 + w * 16 + l16;
    int arow_c = (arow < n) ? arow : (n - 1);   // clamped: garbage rows feed
                                                // only unguarded-unstored D-rows

    f32x4 acc[8];
    #pragma unroll
    for (int t = 0; t < 8; ++t) acc[t] = (f32x4){0.f, 0.f, 0.f, 0.f};

    #pragma unroll
    for (int k0 = 0; k0 < 128; k0 += 32) {
        bf16x8 a;
        if (mode) {
            a = *(const bf16x8*)(sinb + (size_t)arow_c * C + k0 + h * 8);
        } else {
            const float* ap = sinf + (size_t)arow_c * C + k0 + h * 8;
            float4 aa = *(const float4*)ap;
            float4 ab = *(const float4*)(ap + 4);
            union { unsigned short u[8]; bf16x8 v; } pk;
            pk.u[0] = f2bf(aa.x); pk.u[1] = f2bf(aa.y);
            pk.u[2] = f2bf(aa.z); pk.u[3] = f2bf(aa.w);
            pk.u[4] = f2bf(ab.x); pk.u[5] = f2bf(ab.y);
            pk.u[6] = f2bf(ab.z); pk.u[7] = f2bf(ab.w);
            a = pk.v;
        }
        #pragma unroll
        for (int t = 0; t < 8; ++t) {
            int brow = t * 16 + l16;
            int gb = ((k0 >> 3) + h) ^ (brow & 7);
            bf16x8 b = *(const bf16x8*)&wlds[brow * 128 + gb * 8];
            acc[t] = __builtin_amdgcn_mfma_f32_16x16x32_bf16(a, b, acc[t], 0, 0, 0);
        }
    }

    #pragma unroll
    for (int t = 0; t < 8; ++t) {
        int j  = t * 16 + l16;
        float bj = BETA_F * bias[j];
        #pragma unroll
        for (int e2 = 0; e2 < 4; ++e2) {
            int grow = row0 + w * 16 + h * 4 + e2;
            if (grow < n) {
                __builtin_nontemporal_store(acc[t][e2] + bj, &out[(size_t)grow * C + j]);
            }
        }
    }
}

extern "C" void kernel_launch(void* const* d_in, const int* in_sizes, int n_in,
                              void* d_out, int out_size, void* d_ws, size_t ws_size,
                              hipStream_t stream) {
    const float* x   = (const float*)d_in[0];
    const float* x0  = (const float*)d_in[1];
    const float* W   = (const float*)d_in[2];
    const float* b   = (const float*)d_in[3];
    const int*   ei  = (const int*)d_in[4];

    int n = in_sizes[0] / C;
    int e = in_sizes[4] / 2;
    const int* src = ei;
    const int* dst = ei + e;

    // 256B-aligned carving (round 21: a 64B-misaligned y cost 1.5x fill
    // traffic on every 256B row read — alignment is load-bearing).
    char* p = (char*)d_ws;
    auto alloc = [&](size_t bytes) {
        char* q = p;
        p += (bytes + 255) & ~(size_t)255;
        return q;
    };
    int* cnt        = (int*)alloc((size_t)n * 4);
    int* sorted_src = (int*)alloc((size_t)n * KSLOT * 4);
    int* ovf_src    = (int*)alloc((size_t)e * 4);
    int* ovf_dst    = (int*)alloc((size_t)e * 4);
    int* ovf_cnt    = (int*)alloc(256);
    unsigned short* Vb   = (unsigned short*)alloc((size_t)C * C * 2);
    unsigned short* y    = (unsigned short*)alloc((size_t)n * C * 2);
    unsigned short* sb16 = (unsigned short*)alloc((size_t)n * C * 2);

    size_t need = (size_t)(p - (char*)d_ws);
    int mode = (ws_size >= need) ? 1 : 0;

    float* out = (float*)d_out;

    int nb  = (n + 255) / 256;
    int eb  = (e + 255) / 256;
    int ybg = (n * 32 + 255) / 256;

    k_init      <<<nb, 256, 0, stream>>>(W, Vb, cnt, ovf_cnt, n);
    k_hist_place<<<eb, 256, 0, stream>>>(src, dst, cnt, sorted_src,
                                         ovf_src, ovf_dst, ovf_cnt, e);
    k_ybf       <<<ybg, 256, 0, stream>>>(x, cnt, y, n);
    k_gather    <<<(n + 15) / 16, 256, 0, stream>>>(y, x0, sorted_src, cnt,
                                                    ovf_src, ovf_dst, ovf_cnt,
                                                    out, sb16, mode, n);
    k_out       <<<(n + 63) / 64, 256, 0, stream>>>(out, sb16, Vb, b, out, mode, n);
}

// Round 24
// 115.260 us; speedup vs baseline: 1.0573x; 1.0573x over previous
//
#include <hip/hip_runtime.h>
#include <stdint.h>

#define C 128
#define ALPHA_F 0.1f
#define ONE_MINUS_ALPHA 0.9f
// beta = log(THETA/LAYER + 1) = log(1.25)
#define BETA_F 0.22314355131420976f
#define ONE_MINUS_BETA 0.7768564486857902f
#define KSLOT 16

typedef __attribute__((ext_vector_type(8))) short bf16x8;
typedef __attribute__((ext_vector_type(4))) float f32x4;

__device__ inline float bf2f(unsigned short u) {
    union { unsigned int i; float f; } c;
    c.i = ((unsigned int)u) << 16;
    return c.f;
}
__device__ inline unsigned short f2bf(float f) {
    union { float f; unsigned int i; } c;
    c.f = f;
    unsigned int r = (c.i + 0x7FFFu + ((c.i >> 16) & 1u)) >> 16;  // RNE
    return (unsigned short)r;
}

// ---- init: zero cnt + ovf counter + V = (1-beta)*I + beta*W^T (bf16) ----
// (kernel zero, NOT hipMemsetAsync: runtime fill kernel measured 40us/400KB.
//  NOT cooperative mega-kernel: grid.sync measured ~100us-class on 8 XCDs.)
__global__ void k_init(const float* __restrict__ W, unsigned short* __restrict__ Vb,
                       int* __restrict__ cnt, int* __restrict__ ovf_cnt, int n) {
    int i = blockIdx.x * 256 + threadIdx.x;
    if (i == 0) *ovf_cnt = 0;
    if (i < n) cnt[i] = 0;
    if (i < C * C) {
        int j = i >> 7;   // W row = output index
        int c = i & 127;  // k index
        float v = BETA_F * W[i] + ((j == c) ? ONE_MINUS_BETA : 0.f);
        Vb[i] = f2bf(v);
    }
}

// hist + DIRECT placement into fixed-stride CSR. 4 edges/thread via int4
// loads: 4 INDEPENDENT atomic->store chains in flight per thread (the kernel
// is dependent-chain latency-bound: VALU 0.4%, HBM 12%; NT store was
// refuted — 64B line amplification on scattered 4B stores is intrinsic).
__global__ void k_hist_place(const int* __restrict__ src, const int* __restrict__ dst,
                             int* __restrict__ cnt, int* __restrict__ sorted_src,
                             int* __restrict__ ovf_src, int* __restrict__ ovf_dst,
                             int* __restrict__ ovf_cnt, int e) {
    int t = blockIdx.x * blockDim.x + threadIdx.x;
    int i = t * 4;
    if (i + 3 < e) {
        int4 s4 = *(const int4*)(src + i);
        int4 d4 = *(const int4*)(dst + i);
        int r0 = atomicAdd(&cnt[d4.x], 1);
        int r1 = atomicAdd(&cnt[d4.y], 1);
        int r2 = atomicAdd(&cnt[d4.z], 1);
        int r3 = atomicAdd(&cnt[d4.w], 1);
        if (r0 < KSLOT) sorted_src[(size_t)d4.x * KSLOT + r0] = s4.x;
        else { int p = atomicAdd(ovf_cnt, 1); ovf_src[p] = s4.x; ovf_dst[p] = d4.x; }
        if (r1 < KSLOT) sorted_src[(size_t)d4.y * KSLOT + r1] = s4.y;
        else { int p = atomicAdd(ovf_cnt, 1); ovf_src[p] = s4.y; ovf_dst[p] = d4.y; }
        if (r2 < KSLOT) sorted_src[(size_t)d4.z * KSLOT + r2] = s4.z;
        else { int p = atomicAdd(ovf_cnt, 1); ovf_src[p] = s4.z; ovf_dst[p] = d4.z; }
        if (r3 < KSLOT) sorted_src[(size_t)d4.w * KSLOT + r3] = s4.w;
        else { int p = atomicAdd(ovf_cnt, 1); ovf_src[p] = s4.w; ovf_dst[p] = d4.w; }
    } else {
        for (int k = i; k < e; ++k) {
            int d = dst[k];
            int r = atomicAdd(&cnt[d], 1);
            if (r < KSLOT) {
                sorted_src[(size_t)d * KSLOT + r] = src[k];
            } else {
                int p = atomicAdd(ovf_cnt, 1);
                ovf_src[p] = src[k];
                ovf_dst[p] = d;
            }
        }
    }
}

// y[i][:] = bf16(x[i][:] * rsqrt(deg_i+1)); dinv recomputed from cnt (no array)
__global__ void k_ybf(const float* __restrict__ x, const int* __restrict__ cnt,
                      unsigned short* __restrict__ y, int n) {
    int t = blockIdx.x * 256 + threadIdx.x;
    int total = n * 32;
    if (t < total) {
        int i = t >> 5;
        float dv = rsqrtf((float)(cnt[i] + 1));
        float4 v = ((const float4*)x)[t];
        ushort4 o;
        o.x = f2bf(v.x * dv);
        o.y = f2bf(v.y * dv);
        o.z = f2bf(v.z * dv);
        o.w = f2bf(v.w * dv);
        ((ushort4*)y)[t] = o;
    }
}

// per-node accumulate: 8 weight-clamped up-front loads + one 4-wide batch to
// KSLOT=16. eidx = this half-wave's preloaded edge list (coalesced 64B read).
__device__ __forceinline__ float4 acc_node(const ushort4* __restrict__ y4,
                                           int node, int len,
                                           int eidx, int l32, int base) {
    int m = (len < KSLOT) ? len : KSLOT;
    bool b1 = 1 < m, b2 = 2 < m, b3 = 3 < m;
    bool b4 = 4 < m, b5 = 5 < m, b6 = 6 < m, b7 = 7 < m;
    int s0 = __shfl(eidx, base + 0, 64);
    int s1 = __shfl(eidx, base + (b1 ? 1 : 0), 64);
    int s2 = __shfl(eidx, base + (b2 ? 2 : 0), 64);
    int s3 = __shfl(eidx, base + (b3 ? 3 : 0), 64);
    int s4 = __shfl(eidx, base + (b4 ? 4 : 0), 64);
    int s5 = __shfl(eidx, base + (b5 ? 5 : 0), 64);
    int s6 = __shfl(eidx, base + (b6 ? 6 : 0), 64);
    int s7 = __shfl(eidx, base + (b7 ? 7 : 0), 64);
    ushort4 v0 = y4[(size_t)s0 * 32 + l32];
    ushort4 v1 = y4[(size_t)s1 * 32 + l32];
    ushort4 v2 = y4[(size_t)s2 * 32 + l32];
    ushort4 v3 = y4[(size_t)s3 * 32 + l32];
    ushort4 v4 = y4[(size_t)s4 * 32 + l32];
    ushort4 v5 = y4[(size_t)s5 * 32 + l32];
    ushort4 v6 = y4[(size_t)s6 * 32 + l32];
    ushort4 v7 = y4[(size_t)s7 * 32 + l32];
    ushort4 vs = y4[(size_t)node * 32 + l32];   // self-loop row

    float w0 = (0 < m) ? 1.f : 0.f, w1 = b1 ? 1.f : 0.f, w2 = b2 ? 1.f : 0.f, w3 = b3 ? 1.f : 0.f;
    float w4 = b4 ? 1.f : 0.f, w5 = b5 ? 1.f : 0.f, w6 = b6 ? 1.f : 0.f, w7 = b7 ? 1.f : 0.f;

    float4 acc;
    acc.x = bf2f(vs.x) + w0 * bf2f(v0.x) + w1 * bf2f(v1.x) + w2 * bf2f(v2.x) + w3 * bf2f(v3.x)
                       + w4 * bf2f(v4.x) + w5 * bf2f(v5.x) + w6 * bf2f(v6.x) + w7 * bf2f(v7.x);
    acc.y = bf2f(vs.y) + w0 * bf2f(v0.y) + w1 * bf2f(v1.y) + w2 * bf2f(v2.y) + w3 * bf2f(v3.y)
                       + w4 * bf2f(v4.y) + w5 * bf2f(v5.y) + w6 * bf2f(v6.y) + w7 * bf2f(v7.y);
    acc.z = bf2f(vs.z) + w0 * bf2f(v0.z) + w1 * bf2f(v1.z) + w2 * bf2f(v2.z) + w3 * bf2f(v3.z)
                       + w4 * bf2f(v4.z) + w5 * bf2f(v5.z) + w6 * bf2f(v6.z) + w7 * bf2f(v7.z);
    acc.w = bf2f(vs.w) + w0 * bf2f(v0.w) + w1 * bf2f(v1.w) + w2 * bf2f(v2.w) + w3 * bf2f(v3.w)
                       + w4 * bf2f(v4.w) + w5 * bf2f(v5.w) + w6 * bf2f(v6.w) + w7 * bf2f(v7.w);

    for (int j = 8; j < m; j += 4) {     // 9..16 incident edges (one batch)
        bool c1 = (j + 1) < m, c2 = (j + 2) < m, c3 = (j + 3) < m;
        int t0 = __shfl(eidx, base + j, 64);
        int t1 = __shfl(eidx, base + (c1 ? j + 1 : j), 64);
        int t2 = __shfl(eidx, base + (c2 ? j + 2 : j), 64);
        int t3 = __shfl(eidx, base + (c3 ? j + 3 : j), 64);
        ushort4 u0 = y4[(size_t)t0 * 32 + l32];
        ushort4 u1 = y4[(size_t)t1 * 32 + l32];
        ushort4 u2 = y4[(size_t)t2 * 32 + l32];
        ushort4 u3 = y4[(size_t)t3 * 32 + l32];
        float q1 = c1 ? 1.f : 0.f, q2 = c2 ? 1.f : 0.f, q3 = c3 ? 1.f : 0.f;
        acc.x += bf2f(u0.x) + q1 * bf2f(u1.x) + q2 * bf2f(u2.x) + q3 * bf2f(u3.x);
        acc.y += bf2f(u0.y) + q1 * bf2f(u1.y) + q2 * bf2f(u2.y) + q3 * bf2f(u3.y);
        acc.z += bf2f(u0.z) + q1 * bf2f(u1.z) + q2 * bf2f(u2.z) + q3 * bf2f(u3.z);
        acc.w += bf2f(u0.w) + q1 * bf2f(u1.w) + q2 * bf2f(u2.w) + q3 * bf2f(u3.w);
    }
    return acc;
}

// overflow edges for this node (deg > KSLOT): scan the short overflow list,
// filter by dst == node. Correct for any degree distribution.
__device__ __forceinline__ float4 add_ovf(float4 acc, const ushort4* __restrict__ y4,
                                          const int* __restrict__ ovf_src,
                                          const int* __restrict__ ovf_dst,
                                          int oc, int node, int l32) {
    for (int j = 0; j < oc; ++j) {
        if (ovf_dst[j] == node) {
            ushort4 u = y4[(size_t)ovf_src[j] * 32 + l32];
            acc.x += bf2f(u.x);
            acc.y += bf2f(u.y);
            acc.z += bf2f(u.z);
            acc.w += bf2f(u.w);
        }
    }
    return acc;
}

// ---------------- gather + alpha-blend -> s (bf16 ws or fp32 d_out) --------
// 2 nodes per HALF-WAVE, front-loads paired (kernel-level 42.8 -> 40.0us).
__global__ __launch_bounds__(256)
void k_gather(const unsigned short* __restrict__ y, const float* __restrict__ x0,
              const int* __restrict__ sorted_src, const int* __restrict__ cnt,
              const int* __restrict__ ovf_src, const int* __restrict__ ovf_dst,
              const int* __restrict__ ovf_cnt,
              float* __restrict__ soutf, unsigned short* __restrict__ soutb,
              int mode, int n) {
    int tid  = threadIdx.x;
    int l32  = tid & 31;
    int base = tid & 32;
    int hw   = tid >> 5;                  // 0..7 half-wave in block
    int node0 = blockIdx.x * 16 + hw * 2;
    if (node0 >= n) return;
    int node1 = node0 + 1;
    bool ok1 = node1 < n;
    int vn1 = ok1 ? node1 : node0;

    const ushort4* y4 = (const ushort4*)y;
    const f32x4* x04 = (const f32x4*)x0;

    // paired front-loads (all independent); lanes 16..31 pad to self index
    int len0 = cnt[node0];
    int len1 = cnt[vn1];
    int m0 = (len0 < KSLOT) ? len0 : KSLOT;
    int m1 = (len1 < KSLOT) ? len1 : KSLOT;
    int e0 = (l32 < m0) ? sorted_src[(size_t)node0 * KSLOT + l32] : node0;
    int e1 = (l32 < m1) ? sorted_src[(size_t)vn1 * KSLOT + l32] : vn1;
    f32x4 xv0 = __builtin_nontemporal_load(x04 + (size_t)node0 * 32 + l32);
    f32x4 xv1 = __builtin_nontemporal_load(x04 + (size_t)vn1 * 32 + l32);

    float4 a0 = acc_node(y4, node0, len0, e0, l32, base);
    float4 a1 = acc_node(y4, vn1,   len1, e1, l32, base);

    if (len0 > KSLOT || len1 > KSLOT) {   // rare; correct for any input
        int oc = *ovf_cnt;
        if (len0 > KSLOT) a0 = add_ovf(a0, y4, ovf_src, ovf_dst, oc, node0, l32);
        if (len1 > KSLOT) a1 = add_ovf(a1, y4, ovf_src, ovf_dst, oc, vn1, l32);
    }

    float dv0 = rsqrtf((float)(len0 + 1));
    float dv1 = rsqrtf((float)(len1 + 1));

    float4 s0, s1;
    s0.x = ONE_MINUS_ALPHA * (dv0 * a0.x) + ALPHA_F * xv0.x;
    s0.y = ONE_MINUS_ALPHA * (dv0 * a0.y) + ALPHA_F * xv0.y;
    s0.z = ONE_MINUS_ALPHA * (dv0 * a0.z) + ALPHA_F * xv0.z;
    s0.w = ONE_MINUS_ALPHA * (dv0 * a0.w) + ALPHA_F * xv0.w;
    s1.x = ONE_MINUS_ALPHA * (dv1 * a1.x) + ALPHA_F * xv1.x;
    s1.y = ONE_MINUS_ALPHA * (dv1 * a1.y) + ALPHA_F * xv1.y;
    s1.z = ONE_MINUS_ALPHA * (dv1 * a1.z) + ALPHA_F * xv1.z;
    s1.w = ONE_MINUS_ALPHA * (dv1 * a1.w) + ALPHA_F * xv1.w;

    if (mode) {
        unsigned long long p0 =
            (unsigned long long)f2bf(s0.x)
          | ((unsigned long long)f2bf(s0.y) << 16)
          | ((unsigned long long)f2bf(s0.z) << 32)
          | ((unsigned long long)f2bf(s0.w) << 48);
        __builtin_nontemporal_store(
            p0, (unsigned long long*)(soutb + (size_t)node0 * C + l32 * 4));
        if (ok1) {
            unsigned long long p1 =
                (unsigned long long)f2bf(s1.x)
              | ((unsigned long long)f2bf(s1.y) << 16)
              | ((unsigned long long)f2bf(s1.z) << 32)
              | ((unsigned long long)f2bf(s1.w) << 48);
            __builtin_nontemporal_store(
                p1, (unsigned long long*)(soutb + (size_t)node1 * C + l32 * 4));
        }
    } else {
        ((float4*)soutf)[(size_t)node0 * 32 + l32] = s0;
        if (ok1) ((float4*)soutf)[(size_t)node1 * 32 + l32] = s1;
    }
}

// ---------------- MFMA GEMM: out = s @ V + beta*b ----------------
// B (Vb) LDS-staged — round 11 proved B MUST be LDS (32 scattered loads/wave
// from global = 50us kernel). A-fragments straight from global (round 18:
// 126.3 -> 122.9us): only 4 loads/wave/k-step against L3-resident sb16.
__global__ __launch_bounds__(256)
void k_out(const float* __restrict__ sinf, const unsigned short* __restrict__ sinb,
           const unsigned short* __restrict__ Vb, const float* __restrict__ bias,
           float* __restrict__ out, int mode, int n) {
    __shared__ unsigned short wlds[128 * 128];  // 32 KB

    int tid  = threadIdx.x;
    int row0 = blockIdx.x * 64;

    const uint4* Vb16 = (const uint4*)Vb;
    for (int i = tid; i < 2048; i += 256) {
        int j = i >> 4;
        int g = i & 15;
        uint4 v = Vb16[i];
        *(uint4*)&wlds[j * 128 + (g ^ (j & 7)) * 8] = v;
    }
    __syncthreads();

    int w    = tid >> 6;
    int lane = tid & 63;
    int l16  = lane & 15;
    int h    = lane >> 4;
    int arow = row0 + w * 16 + l16;
    int arow_c = (arow < n) ? arow : (n - 1);   // clamped: garbage rows feed
                                                // only unguarded-unstored D-rows

    f32x4 acc[8];
    #pragma unroll
    for (int t = 0; t < 8; ++t) acc[t] = (f32x4){0.f, 0.f, 0.f, 0.f};

    #pragma unroll
    for (int k0 = 0; k0 < 128; k0 += 32) {
        bf16x8 a;
        if (mode) {
            a = *(const bf16x8*)(sinb + (size_t)arow_c * C + k0 + h * 8);
        } else {
            const float* ap = sinf + (size_t)arow_c * C + k0 + h * 8;
            float4 aa = *(const float4*)ap;
            float4 ab = *(const float4*)(ap + 4);
            union { unsigned short u[8]; bf16x8 v; } pk;
            pk.u[0] = f2bf(aa.x); pk.u[1] = f2bf(aa.y);
            pk.u[2] = f2bf(aa.z); pk.u[3] = f2bf(aa.w);
            pk.u[4] = f2bf(ab.x); pk.u[5] = f2bf(ab.y);
            pk.u[6] = f2bf(ab.z); pk.u[7] = f2bf(ab.w);
            a = pk.v;
        }
        #pragma unroll
        for (int t = 0; t < 8; ++t) {
            int brow = t * 16 + l16;
            int gb = ((k0 >> 3) + h) ^ (brow & 7);
            bf16x8 b = *(const bf16x8*)&wlds[brow * 128 + gb * 8];
            acc[t] = __builtin_amdgcn_mfma_f32_16x16x32_bf16(a, b, acc[t], 0, 0, 0);
        }
    }

    #pragma unroll
    for (int t = 0; t < 8; ++t) {
        int j  = t * 16 + l16;
        float bj = BETA_F * bias[j];
        #pragma unroll
        for (int e2 = 0; e2 < 4; ++e2) {
            int grow = row0 + w * 16 + h * 4 + e2;
            if (grow < n) {
                __builtin_nontemporal_store(acc[t][e2] + bj, &out[(size_t)grow * C + j]);
            }
        }
    }
}

extern "C" void kernel_launch(void* const* d_in, const int* in_sizes, int n_in,
                              void* d_out, int out_size, void* d_ws, size_t ws_size,
                              hipStream_t stream) {
    const float* x   = (const float*)d_in[0];
    const float* x0  = (const float*)d_in[1];
    const float* W   = (const float*)d_in[2];
    const float* b   = (const float*)d_in[3];
    const int*   ei  = (const int*)d_in[4];

    int n = in_sizes[0] / C;
    int e = in_sizes[4] / 2;
    const int* src = ei;
    const int* dst = ei + e;

    // 256B-aligned carving (round 21: a 64B-misaligned y cost 1.5x fill
    // traffic on every 256B row read — alignment is load-bearing).
    char* p = (char*)d_ws;
    auto alloc = [&](size_t bytes) {
        char* q = p;
        p += (bytes + 255) & ~(size_t)255;
        return q;
    };
    int* cnt        = (int*)alloc((size_t)n * 4);
    int* sorted_src = (int*)alloc((size_t)n * KSLOT * 4);
    int* ovf_src    = (int*)alloc((size_t)e * 4);
    int* ovf_dst    = (int*)alloc((size_t)e * 4);
    int* ovf_cnt    = (int*)alloc(256);
    unsigned short* Vb   = (unsigned short*)alloc((size_t)C * C * 2);
    unsigned short* y    = (unsigned short*)alloc((size_t)n * C * 2);
    unsigned short* sb16 = (unsigned short*)alloc((size_t)n * C * 2);

    size_t need = (size_t)(p - (char*)d_ws);
    int mode = (ws_size >= need) ? 1 : 0;

    float* out = (float*)d_out;

    int nb  = (n + 255) / 256;
    int eb4 = (e / 4 + 255) / 256;
    int ybg = (n * 32 + 255) / 256;

    k_init      <<<nb, 256, 0, stream>>>(W, Vb, cnt, ovf_cnt, n);
    k_hist_place<<<eb4, 256, 0, stream>>>(src, dst, cnt, sorted_src,
                                          ovf_src, ovf_dst, ovf_cnt, e);
    k_ybf       <<<ybg, 256, 0, stream>>>(x, cnt, y, n);
    k_gather    <<<(n + 15) / 16, 256, 0, stream>>>(y, x0, sorted_src, cnt,
                                                    ovf_src, ovf_dst, ovf_cnt,
                                                    out, sb16, mode, n);
    k_out       <<<(n + 63) / 64, 256, 0, stream>>>(out, sb16, Vb, b, out, mode, n);
}